// Round 1
// 3634.171 us; speedup vs baseline: 1.0306x; 1.0306x over previous
//
#include <hip/hip_runtime.h>

typedef _Float16 half8  __attribute__((ext_vector_type(8)));
typedef _Float16 half4v __attribute__((ext_vector_type(4)));
typedef float    float4v __attribute__((ext_vector_type(4)));

#define MFMA16(a, b, c) __builtin_amdgcn_mfma_f32_16x16x32_f16((a), (b), (c), 0, 0, 0)

constexpr int BB = 256;   // batch
constexpr int LL = 512;   // encoder seq len
constexpr int DD = 64;    // input dim
constexpr int HH = 1024;  // hidden (enc == dec)
constexpr int SS = 24;    // decoder steps

// workspace layout (~17.8 MB total)
constexpr size_t OFF_X2    = 0;                          // [B][L][D] f16 (smoothed input)
constexpr size_t SZ_X2     = (size_t)BB * LL * DD * 2;
constexpr size_t OFF_HBUF  = OFF_X2 + SZ_X2;             // [2][B][H] f16 h double-buffer
constexpr size_t SZ_HBUF   = (size_t)2 * BB * HH * 2;
constexpr size_t OFF_OUTP  = OFF_HBUF + SZ_HBUF;         // [B][S][2] f32 pre-desmooth out
constexpr size_t SZ_OUTP   = (size_t)BB * SS * 2 * 4;
constexpr size_t OFF_BAR   = OFF_OUTP + SZ_OUTP;         // grid leader counter
constexpr size_t SZ_BAR    = 32 * 4;
constexpr size_t OFF_EFLAG = OFF_BAR + SZ_BAR;           // 8 groups × 32 epoch flags, 64B stride
constexpr size_t SZ_EFLAG  = (size_t)8 * 32 * 16 * 4;
constexpr size_t OFF_ST11  = OFF_EFLAG + SZ_EFLAG;       // [B][2] f32
constexpr size_t OFF_ST12  = OFF_ST11 + 2048;            // [B][2] f32
constexpr size_t OFF_FLAG  = OFF_ST12 + 2048;            // [256] u32 init-free flag barrier (NOT pre-zeroed)

// ---- agent-scope (cross-XCD coherent, cache-bypassing) accessors ----
__device__ __forceinline__ void agstore_u64(void* p, unsigned long long v) {
  __hip_atomic_store((unsigned long long*)p, v, __ATOMIC_RELAXED, __HIP_MEMORY_SCOPE_AGENT);
}
__device__ __forceinline__ void agstore_u32(void* p, unsigned v) {
  __hip_atomic_store((unsigned*)p, v, __ATOMIC_RELAXED, __HIP_MEMORY_SCOPE_AGENT);
}
__device__ __forceinline__ unsigned agload_u32(const unsigned* p) {
  return __hip_atomic_load(p, __ATOMIC_RELAXED, __HIP_MEMORY_SCOPE_AGENT);
}
__device__ __forceinline__ half8 agload_h8(const _Float16* p) {
  const unsigned long long* q = (const unsigned long long*)p;
  union { unsigned long long u[2]; half8 h; } cv;
  cv.u[0] = __hip_atomic_load(q,     __ATOMIC_RELAXED, __HIP_MEMORY_SCOPE_AGENT);
  cv.u[1] = __hip_atomic_load(q + 1, __ATOMIC_RELAXED, __HIP_MEMORY_SCOPE_AGENT);
  return cv.h;
}
__device__ __forceinline__ void agstore_h4(void* p, half4v h) {
  union { half4v h; unsigned long long u; } cv; cv.h = h;
  agstore_u64(p, cv.u);
}

template <int M, int N>
__device__ __forceinline__ void zero_acc(float4v (&a)[M][N]) {
  #pragma unroll
  for (int m = 0; m < M; ++m) {
    #pragma unroll
    for (int n = 0; n < N; ++n) {
      #pragma unroll
      for (int r = 0; r < 4; ++r) a[m][n][r] = 0.f;
    }
  }
}

// convert 8 consecutive f32 -> f16 MFMA fragment
__device__ __forceinline__ half8 ld_w8_f16(const float* p) {
  float4 f0 = *(const float4*)(p);
  float4 f1 = *(const float4*)(p + 4);
  half8 h;
  h[0] = (_Float16)f0.x; h[1] = (_Float16)f0.y; h[2] = (_Float16)f0.z; h[3] = (_Float16)f0.w;
  h[4] = (_Float16)f1.x; h[5] = (_Float16)f1.y; h[6] = (_Float16)f1.z; h[7] = (_Float16)f1.w;
  return h;
}

// Load Whh-style [3072][1024] weight slice for (hidden-slice s, K-quarter w) into
// register-resident B-fragments (layout: lane holds B[k][ncol], ncol=lane&15, k=(lane>>4)*8+j).
__device__ __forceinline__ void load_W_frags(const float* __restrict__ W, int s, int w,
                                             int lane, half8 BW[6][8]) {
  const int l15 = lane & 15, lq = lane >> 4;
  #pragma unroll
  for (int n = 0; n < 6; ++n) {
    const int row = (n >> 1) * 1024 + s * 32 + (n & 1) * 16 + l15;
    const float* rp = W + (size_t)row * HH + (w << 8) + (lq << 3);
    #pragma unroll
    for (int ks = 0; ks < 8; ++ks) BW[n][ks] = ld_w8_f16(rp + ks * 32);
  }
}

// ---- all-to-all epoch-flag group barrier (no RMW contention) ----
// arrive: after syncthreads (all waves' agent stores drained to coherence point),
// block stores its own epoch flag — one store, private 64B line.
__device__ __forceinline__ void bar_arrive(unsigned* ef, int lb, unsigned ep1) {
  __syncthreads();
  if (threadIdx.x == 0) agstore_u32(&ef[lb * 16], ep1);
}
// full-group wait (used once at the end): lanes 0..31 of wave 0 poll all 32 flags.
__device__ __forceinline__ void bar_wait(unsigned* ef, unsigned ep) {
  if (threadIdx.x < 32) {
    while (agload_u32(&ef[threadIdx.x * 16]) < ep)
      __builtin_amdgcn_s_sleep(1);
  }
  __syncthreads();
}

// per-wave producer wait: wave w consumes K-columns produced by blocks
// s' = w*8 .. w*8+7 only. Lanes 0..7 gather those 8 epoch flags with one
// vector load; ballot; spin until all 8 >= ep. No __syncthreads — waves of a
// block decouple; LDS hazards are covered by the existing per-step barriers.
__device__ __forceinline__ void wait_my8(unsigned* ef, int w8, unsigned ep, int lane) {
  for (;;) {
    unsigned f = 0xFFFFFFFFu;
    if (lane < 8) f = agload_u32(&ef[(w8 + lane) * 16]);
    unsigned long long m = __ballot(f >= ep);
    if (m == ~0ull) break;
    __builtin_amdgcn_s_sleep(1);
  }
}

// Init-free grid barrier: overwrites poison, needs no pre-zeroed memory.
__device__ __forceinline__ void flag_barrier(unsigned* flags, int blk, int tid, unsigned val) {
  __syncthreads();
  if (tid == 0) agstore_u32(&flags[blk], val);
  while (agload_u32(&flags[tid]) != val)
    __builtin_amdgcn_s_sleep(2);
  __syncthreads();
}

// partial sums: P[wave][local_row 0..31][col 0..95(+pad)]  pitch 97
#define PS(rw, cl) (P[(rw)*97 + (cl)] + P[3104 + (rw)*97 + (cl)] + \
                    P[6208 + (rw)*97 + (cl)] + P[9312 + (rw)*97 + (cl)])

__global__ __launch_bounds__(256, 1) void ts_fused(
    const float* __restrict__ x,
    const float* __restrict__ eWih, const float* __restrict__ eWhh,
    const float* __restrict__ ebih, const float* __restrict__ ebhh,
    const float* __restrict__ dWih, const float* __restrict__ dWhh,
    const float* __restrict__ dbih, const float* __restrict__ dbhh,
    const float* __restrict__ fciW, const float* __restrict__ fcib,
    const float* __restrict__ fcW,  const float* __restrict__ fcb,
    float* __restrict__ out, char* __restrict__ ws) {
  __shared__ float P[4 * 32 * 97];  // per-wave K-partial sums (49,664 B)
  __shared__ float Q[32 * 97];      // enc: inn ; dec: gi_dec (constant over steps)

  _Float16* x2     = (_Float16*)(ws + OFF_X2);
  _Float16* hbuf   = (_Float16*)(ws + OFF_HBUF);
  float* outp      = (float*)(ws + OFF_OUTP);
  unsigned* bar    = (unsigned*)(ws + OFF_BAR);
  unsigned* eflags = (unsigned*)(ws + OFF_EFLAG);
  float* st11      = (float*)(ws + OFF_ST11);
  float* st12      = (float*)(ws + OFF_ST12);
  unsigned* flags  = (unsigned*)(ws + OFF_FLAG);

  const int tid  = threadIdx.x;
  const int blk  = blockIdx.x;
  const int lane = tid & 63;
  const int w    = tid >> 6;   // wave = K-quarter
  const int w8   = w << 3;     // first producer block of this wave's K-quarter
  const int l15  = lane & 15;
  const int lq   = lane >> 4;
  const int g    = blk & 7;    // batch group: rows g*32..g*32+31
  const int s    = blk >> 3;   // hidden slice: cols s*32..s*32+31 (also local-block id in group)
  const int eb   = tid >> 3;   // epilogue: local batch row 0..31
  const int jq   = tid & 7;    // epilogue: j-quad, j = jq*4+e
  const int colb = s * 32 + jq * 4;

  // ---------------- phase 0: smoothing (64 blk × 64 thr × 4 chains) + zero-init ----------------
  if (blk < 64) {
    if (tid < 64) {
      const int idx = blk * 64 + tid;   // 4096 threads: (b, d-quad)
      const int b = idx >> 4, dq = idx & 15, d = dq * 4;
      const float* xp = x + (size_t)b * LL * DD + d;
      _Float16* x2p = x2 + (size_t)b * LL * DD + d;
      float v1[4] = {0.f, 0.f, 0.f, 0.f}, v2[4] = {0.f, 0.f, 0.f, 0.f};
      #pragma unroll 1
      for (int t0 = 0; t0 < LL; t0 += 8) {
        // batch 8 independent loads up front (8-deep latency hiding)
        float4 xb[8];
        #pragma unroll
        for (int u = 0; u < 8; ++u)
          xb[u] = *(const float4*)(xp + (size_t)(t0 + u) * DD);
        #pragma unroll
        for (int u = 0; u < 8; ++u) {
          const int t = t0 + u;
          const float xe[4] = {xb[u].x, xb[u].y, xb[u].z, xb[u].w};
          half4v hv;
          #pragma unroll
          for (int e = 0; e < 4; ++e) {
            v1[e] = (t == 0) ? xe[e] : 0.7f * xe[e] + 0.3f * v1[e];  // alpha=0.3 pass
            v2[e] = (t == 0) ? v1[e] : 0.5f * v1[e] + 0.5f * v2[e];  // beta=0.5 pass
            hv[e] = (_Float16)v2[e];
          }
          agstore_h4(x2p + (size_t)t * DD, hv);  // write-through (cross-XCD read later)
        }
      }
      if (dq == 0) {  // COLS = {1,2}
        union { float f[2]; unsigned long long u; } c1, c2;
        c1.f[0] = v1[1]; c1.f[1] = v1[2];
        c2.f[0] = v2[1]; c2.f[1] = v2[2];
        agstore_u64(&st11[b * 2], c1.u);
        agstore_u64(&st12[b * 2], c2.u);
      }
    }
  } else {
    // zero hbuf (h0=0), outp, bar, eflags — contiguous region, write-through
    unsigned long long* zr = (unsigned long long*)(ws + OFF_HBUF);
    const int NZ = (int)((SZ_HBUF + SZ_OUTP + SZ_BAR + SZ_EFLAG) / 8);
    for (int i = (blk - 64) * 256 + tid; i < NZ; i += 192 * 256) agstore_u64(&zr[i], 0ull);
  }

  // grid barrier #1 — init-free
  flag_barrier(flags, blk, tid, 1u);

  unsigned* ef      = eflags + g * 32 * 16;  // this group's 32 epoch flags
  unsigned* gridbar = bar;

  // ---------------- encoder ----------------
  half8 BW[6][8];                       // Whh slice, register-stationary (192 VGPRs)
  load_W_frags(eWhh, s, w, lane, BW);
  half8 BWi[6][2];                      // Wih slice (K=64), wave 0 only
  if (w == 0) {
    #pragma unroll
    for (int n = 0; n < 6; ++n) {
      const int row = (n >> 1) * 1024 + s * 32 + (n & 1) * 16 + l15;
      const float* rp = eWih + (size_t)row * DD + (lq << 3);
      #pragma unroll
      for (int ks = 0; ks < 2; ++ks) BWi[n][ks] = ld_w8_f16(rp + ks * 32);
    }
  }
  float ebr[4], ebz[4], ebin[4], ebhn[4];
  #pragma unroll
  for (int e = 0; e < 4; ++e) {
    const int c = colb + e;
    ebr[e]  = ebih[c] + ebhh[c];                 // r: biases merge
    ebz[e]  = ebih[1024 + c] + ebhh[1024 + c];   // z: biases merge
    ebin[e] = ebih[2048 + c];                    // n: stays separate (r * (hn + bhh_n))
    ebhn[e] = ebhh[2048 + c];
  }
  float hold[4] = {0.f, 0.f, 0.f, 0.f};  // fp32 master h for owned (b,j) elements

  #pragma unroll 1
  for (int t = 0; t < LL; ++t) {
    const _Float16* hc = hbuf + (size_t)(t & 1) * BB * HH;
    _Float16* hnx = hbuf + (size_t)((t + 1) & 1) * BB * HH;

    float4v acc[2][6], accI[2][2];
    zero_acc(acc);
    zero_acc(accI);

    if (w == 0) {  // gi = x2_t @ Wih^T : r,z seed acc; inn kept separate in accI
      #pragma unroll
      for (int ks = 0; ks < 2; ++ks) {
        const _Float16* ap = x2 + (size_t)(g * 32 + l15) * (LL * DD) + (size_t)t * DD + ks * 32 + (lq << 3);
        half8 a0 = *(const half8*)ap;                        // write-once data: plain load safe
        half8 a1 = *(const half8*)(ap + (size_t)16 * LL * DD);
        #pragma unroll
        for (int n = 0; n < 6; ++n) {
          if (n < 4) {
            acc[0][n] = MFMA16(a0, BWi[n][ks], acc[0][n]);
            acc[1][n] = MFMA16(a1, BWi[n][ks], acc[1][n]);
          } else {
            accI[0][n - 4] = MFMA16(a0, BWi[n][ks], accI[0][n - 4]);
            accI[1][n - 4] = MFMA16(a1, BWi[n][ks], accI[1][n - 4]);
          }
        }
      }
    }
    // wait only for THIS wave's 8 producers (K-quarter w); t=0: h0 ready via grid barrier #1
    if (t > 0) wait_my8(ef, w8, (unsigned)t, lane);
    // gh partial = h_t[g-rows, K-quarter w] @ Whh^T  (h: agent loads — rewritten data)
    #pragma unroll
    for (int ks = 0; ks < 8; ++ks) {
      const _Float16* ap = hc + (size_t)(g * 32 + l15) * HH + (w << 8) + ks * 32 + (lq << 3);
      half8 a0 = agload_h8(ap);
      half8 a1 = agload_h8(ap + 16 * HH);
      #pragma unroll
      for (int n = 0; n < 6; ++n) {
        acc[0][n] = MFMA16(a0, BW[n][ks], acc[0][n]);
        acc[1][n] = MFMA16(a1, BW[n][ks], acc[1][n]);
      }
    }
    {  // partials -> LDS  (C-layout: row = m*16+lq*4+r, col = gate*32+(n&1)*16+l15)
      float* Pw = P + w * 3104;
      #pragma unroll
      for (int m = 0; m < 2; ++m) {
        const int row0 = m * 16 + lq * 4;
        #pragma unroll
        for (int n = 0; n < 6; ++n) {
          const int col = (n >> 1) * 32 + (n & 1) * 16 + l15;
          #pragma unroll
          for (int r = 0; r < 4; ++r) Pw[(row0 + r) * 97 + col] = acc[m][n][r];
        }
      }
      if (w == 0) {
        #pragma unroll
        for (int m = 0; m < 2; ++m) {
          const int row0 = m * 16 + lq * 4;
          #pragma unroll
          for (int n2 = 0; n2 < 2; ++n2) {
            const int col = n2 * 16 + l15;
            #pragma unroll
            for (int r = 0; r < 4; ++r) Q[(row0 + r) * 97 + col] = accI[m][n2][r];
          }
        }
      }
    }
    __syncthreads();
    {  // GRU epilogue, fp32
      half4v hh;
      #pragma unroll
      for (int e = 0; e < 4; ++e) {
        const int j = jq * 4 + e;
        const float Sr = PS(eb, j);        // ir+hr
        const float Sz = PS(eb, 32 + j);   // iz+hz
        const float Hn = PS(eb, 64 + j);   // hn only
        const float rr = 1.f / (1.f + __expf(-(Sr + ebr[e])));
        const float zz = 1.f / (1.f + __expf(-(Sz + ebz[e])));
        const float aN = (Q[eb * 97 + j] + ebin[e]) + rr * (Hn + ebhn[e]);
        const float nn = 1.f - 2.f / (1.f + __expf(2.f * aN));
        const float hv = (1.f - zz) * nn + zz * hold[e];
        hold[e] = hv;
        hh[e] = (_Float16)hv;
      }
      agstore_h4(hnx + (size_t)(g * 32 + eb) * HH + s * 32 + jq * 4, hh);
    }
    bar_arrive(ef, s, (unsigned)(t + 1));
  }

  // ---------------- D0: gi_dec = hT@dWih^T + dbih (-> Q), h0d = hT@fciW^T + fcib ----------------
  {
    wait_my8(ef, w8, (unsigned)LL, lane);  // hT ready (this wave's K-quarter)
    const _Float16* hT = hbuf;   // parity: after 512 steps hT lives in buf0
    float4v acc[2][6];
    zero_acc(acc);
    #pragma unroll 1
    for (int ks = 0; ks < 8; ++ks) {
      const _Float16* ap = hT + (size_t)(g * 32 + l15) * HH + (w << 8) + ks * 32 + (lq << 3);
      half8 a0 = agload_h8(ap);
      half8 a1 = agload_h8(ap + 16 * HH);
      #pragma unroll
      for (int n = 0; n < 6; ++n) {
        const int row = (n >> 1) * 1024 + s * 32 + (n & 1) * 16 + l15;
        half8 bf = ld_w8_f16(dWih + (size_t)row * HH + (w << 8) + ks * 32 + (lq << 3));
        acc[0][n] = MFMA16(a0, bf, acc[0][n]);
        acc[1][n] = MFMA16(a1, bf, acc[1][n]);
      }
    }
    {
      float* Pw = P + w * 3104;
      #pragma unroll
      for (int m = 0; m < 2; ++m) {
        const int row0 = m * 16 + lq * 4;
        #pragma unroll
        for (int n = 0; n < 6; ++n) {
          const int col = (n >> 1) * 32 + (n & 1) * 16 + l15;
          #pragma unroll
          for (int r = 0; r < 4; ++r) Pw[(row0 + r) * 97 + col] = acc[m][n][r];
        }
      }
    }
    __syncthreads();
    #pragma unroll
    for (int e = 0; e < 4; ++e) {   // Q <- gi_dec (+ dbih), constant for all 24 steps
      const int j = jq * 4 + e;
      #pragma unroll
      for (int gate = 0; gate < 3; ++gate) {
        const int col = gate * 32 + j;
        Q[eb * 97 + col] = PS(eb, col) + dbih[gate * 1024 + s * 32 + j];
      }
    }
    __syncthreads();
    // h0d = hT @ fciW^T + fcib  (same K-quarter producers already confirmed >= LL)
    float4v acc2[2][2];
    zero_acc(acc2);
    #pragma unroll 1
    for (int ks = 0; ks < 8; ++ks) {
      const _Float16* ap = hT + (size_t)(g * 32 + l15) * HH + (w << 8) + ks * 32 + (lq << 3);
      half8 a0 = agload_h8(ap);
      half8 a1 = agload_h8(ap + 16 * HH);
      #pragma unroll
      for (int n2 = 0; n2 < 2; ++n2) {
        const int row = s * 32 + n2 * 16 + l15;
        half8 bf = ld_w8_f16(fciW + (size_t)row * HH + (w << 8) + ks * 32 + (lq << 3));
        acc2[0][n2] = MFMA16(a0, bf, acc2[0][n2]);
        acc2[1][n2] = MFMA16(a1, bf, acc2[1][n2]);
      }
    }
    {
      float* Pw = P + w * 3104;
      #pragma unroll
      for (int m = 0; m < 2; ++m) {
        const int row0 = m * 16 + lq * 4;
        #pragma unroll
        for (int n2 = 0; n2 < 2; ++n2) {
          const int col = n2 * 16 + l15;
          #pragma unroll
          for (int r = 0; r < 4; ++r) Pw[(row0 + r) * 97 + col] = acc2[m][n2][r];
        }
      }
    }
    __syncthreads();
    {
      half4v hh;
      #pragma unroll
      for (int e = 0; e < 4; ++e) {
        const int j = jq * 4 + e;
        const float v = PS(eb, j) + fcib[s * 32 + j];
        hold[e] = v;
        hh[e] = (_Float16)v;
      }
      // write h0d to buf1 (buf0 = hT still being read by group peers until their waits pass)
      agstore_h4(hbuf + (size_t)BB * HH + (size_t)(g * 32 + eb) * HH + s * 32 + jq * 4, hh);
    }
    bar_arrive(ef, s, (unsigned)(LL + 1));
  }

  // ---------------- decoder ----------------
  load_W_frags(dWhh, s, w, lane, BW);  // reuse register file
  float dbr_[4], dbz_[4], dbn_[4], fw0[4], fw1[4];
  #pragma unroll
  for (int e = 0; e < 4; ++e) {
    const int c = colb + e;
    dbr_[e] = dbhh[c];
    dbz_[e] = dbhh[1024 + c];
    dbn_[e] = dbhh[2048 + c];
    fw0[e] = fcW[c];           // fc_W [2][1024]
    fw1[e] = fcW[1024 + c];
  }
  #pragma unroll 1
  for (int t = 0; t < SS; ++t) {
    wait_my8(ef, w8, (unsigned)(LL + 1 + t), lane);
    const _Float16* hc = hbuf + (size_t)((t + 1) & 1) * BB * HH;  // t=0 reads buf1 (h0d)
    _Float16* hnx = hbuf + (size_t)(t & 1) * BB * HH;
    float4v acc[2][6];
    zero_acc(acc);
    #pragma unroll
    for (int ks = 0; ks < 8; ++ks) {
      const _Float16* ap = hc + (size_t)(g * 32 + l15) * HH + (w << 8) + ks * 32 + (lq << 3);
      half8 a0 = agload_h8(ap);
      half8 a1 = agload_h8(ap + 16 * HH);
      #pragma unroll
      for (int n = 0; n < 6; ++n) {
        acc[0][n] = MFMA16(a0, BW[n][ks], acc[0][n]);
        acc[1][n] = MFMA16(a1, BW[n][ks], acc[1][n]);
      }
    }
    {
      float* Pw = P + w * 3104;
      #pragma unroll
      for (int m = 0; m < 2; ++m) {
        const int row0 = m * 16 + lq * 4;
        #pragma unroll
        for (int n = 0; n < 6; ++n) {
          const int col = (n >> 1) * 32 + (n & 1) * 16 + l15;
          #pragma unroll
          for (int r = 0; r < 4; ++r) Pw[(row0 + r) * 97 + col] = acc[m][n][r];
        }
      }
    }
    __syncthreads();
    {
      half4v hh;
      float p0 = 0.f, p1 = 0.f;
      #pragma unroll
      for (int e = 0; e < 4; ++e) {
        const int j = jq * 4 + e;
        const float rr = 1.f / (1.f + __expf(-(PS(eb, j) + Q[eb * 97 + j] + dbr_[e])));
        const float zz = 1.f / (1.f + __expf(-(PS(eb, 32 + j) + Q[eb * 97 + 32 + j] + dbz_[e])));
        const float aN = Q[eb * 97 + 64 + j] + rr * (PS(eb, 64 + j) + dbn_[e]);
        const float nn = 1.f - 2.f / (1.f + __expf(2.f * aN));
        const float hv = (1.f - zz) * nn + zz * hold[e];
        hold[e] = hv;
        hh[e] = (_Float16)hv;
        p0 += hv * fw0[e];
        p1 += hv * fw1[e];
      }
      agstore_h4(hnx + (size_t)(g * 32 + eb) * HH + s * 32 + jq * 4, hh);
      // fc fused: reduce over this CU's 32 hidden cols (8 adjacent lanes share a batch row)
      p0 += __shfl_xor(p0, 1); p0 += __shfl_xor(p0, 2); p0 += __shfl_xor(p0, 4);
      p1 += __shfl_xor(p1, 1); p1 += __shfl_xor(p1, 2); p1 += __shfl_xor(p1, 4);
      if (jq == 0) {
        atomicAdd(&outp[((g * 32 + eb) * SS + t) * 2 + 0], p0);
        atomicAdd(&outp[((g * 32 + eb) * SS + t) * 2 + 1], p1);
      }
    }
    bar_arrive(ef, s, (unsigned)(LL + 2 + t));
  }

  // ---------------- grid barrier #2: group flag-barrier, then 8 leader RMWs ----------------
  bar_wait(ef, (unsigned)(LL + 1 + SS));   // group done (outp atomics drained pre-arrive)
  if (s == 0 && tid == 0) atomicAdd(gridbar, 1u);
  if (tid == 0) {
    while (agload_u32(gridbar) < 8u) __builtin_amdgcn_s_sleep(1);
  }
  __syncthreads();

  // ---------------- final: fc bias + two shifted de-smoothing passes ----------------
  if (blk < 2) {
    const int t5 = blk * 256 + tid;   // 512 threads: (b, c)
    const int b = t5 >> 1, c = t5 & 1;
    const float s2v = st12[b * 2 + c];
    const float s1v = st11[b * 2 + c];
    const float bias = fcb[c];
    float o0p = 0.f, o1p = 0.f;
    #pragma unroll 1
    for (int t = 0; t < SS; ++t) {
      const float o0 = outp[(b * SS + t) * 2 + c] + bias;
      const float o1 = 2.f * o0 - ((t == 0) ? s2v : o0p);              // (o0-0.5*st2)/0.5
      const float o2 = (o1 - 0.3f * ((t == 0) ? s1v : o1p)) * (1.f / 0.7f);
      o0p = o0; o1p = o1;
      out[b * 48 + t * 2 + c] = o2;
    }
  }

  // replay-safety: leave flags at 0 for the next launch (all blocks have passed
  // flag-barrier #1 before any block reaches here — guaranteed by grid barrier #2)
  if (tid == 0) agstore_u32(&flags[blk], 0u);
}

extern "C" void kernel_launch(void* const* d_in, const int* in_sizes, int n_in,
                              void* d_out, int out_size, void* d_ws, size_t ws_size,
                              hipStream_t stream) {
  (void)in_sizes; (void)n_in; (void)out_size; (void)ws_size;
  const float* x    = (const float*)d_in[0];
  const float* eWih = (const float*)d_in[1];
  const float* eWhh = (const float*)d_in[2];
  const float* ebih = (const float*)d_in[3];
  const float* ebhh = (const float*)d_in[4];
  const float* dWih = (const float*)d_in[5];
  const float* dWhh = (const float*)d_in[6];
  const float* dbih = (const float*)d_in[7];
  const float* dbhh = (const float*)d_in[8];
  const float* fciW = (const float*)d_in[9];
  const float* fcib = (const float*)d_in[10];
  const float* fcW  = (const float*)d_in[11];
  const float* fcb  = (const float*)d_in[12];
  float* out = (float*)d_out;
  char* ws = (char*)d_ws;

  ts_fused<<<dim3(256), dim3(256), 0, stream>>>(
      x, eWih, eWhh, ebih, ebhh, dWih, dWhh, dbih, dbhh,
      fciW, fcib, fcW, fcb, out, ws);
}

// Round 2
// 3077.416 us; speedup vs baseline: 1.2170x; 1.1809x over previous
//
#include <hip/hip_runtime.h>

typedef _Float16 half8  __attribute__((ext_vector_type(8)));
typedef _Float16 half4v __attribute__((ext_vector_type(4)));
typedef float    float4v __attribute__((ext_vector_type(4)));

#define MFMA16(a, b, c) __builtin_amdgcn_mfma_f32_16x16x32_f16((a), (b), (c), 0, 0, 0)

constexpr int BB = 256;   // batch
constexpr int LL = 512;   // encoder seq len
constexpr int DD = 64;    // input dim
constexpr int HH = 1024;  // hidden (enc == dec)
constexpr int SS = 24;    // decoder steps

// workspace layout (~17.8 MB total)
constexpr size_t OFF_X2    = 0;                          // [B][L][D] f16 (smoothed input)
constexpr size_t SZ_X2     = (size_t)BB * LL * DD * 2;
constexpr size_t OFF_HBUF  = OFF_X2 + SZ_X2;             // [2][B][H] f16 h double-buffer
constexpr size_t SZ_HBUF   = (size_t)2 * BB * HH * 2;
constexpr size_t OFF_OUTP  = OFF_HBUF + SZ_HBUF;         // [B][S][2] f32 pre-desmooth out
constexpr size_t SZ_OUTP   = (size_t)BB * SS * 2 * 4;
constexpr size_t OFF_BAR   = OFF_OUTP + SZ_OUTP;         // grid leader counter
constexpr size_t SZ_BAR    = 32 * 4;
constexpr size_t OFF_EFLAG = OFF_BAR + SZ_BAR;           // 8 groups × 32 epoch flags, 64B stride
constexpr size_t SZ_EFLAG  = (size_t)8 * 32 * 16 * 4;
constexpr size_t OFF_ST11  = OFF_EFLAG + SZ_EFLAG;       // [B][2] f32
constexpr size_t OFF_ST12  = OFF_ST11 + 2048;            // [B][2] f32
constexpr size_t OFF_FLAG  = OFF_ST12 + 2048;            // [256] u32 init-free flag barrier (NOT pre-zeroed)

// ---- agent-scope (cross-XCD coherent, cache-bypassing) accessors ----
__device__ __forceinline__ void agstore_u64(void* p, unsigned long long v) {
  __hip_atomic_store((unsigned long long*)p, v, __ATOMIC_RELAXED, __HIP_MEMORY_SCOPE_AGENT);
}
__device__ __forceinline__ void agstore_u32(void* p, unsigned v) {
  __hip_atomic_store((unsigned*)p, v, __ATOMIC_RELAXED, __HIP_MEMORY_SCOPE_AGENT);
}
__device__ __forceinline__ unsigned agload_u32(const unsigned* p) {
  return __hip_atomic_load(p, __ATOMIC_RELAXED, __HIP_MEMORY_SCOPE_AGENT);
}
__device__ __forceinline__ half8 agload_h8(const _Float16* p) {
  const unsigned long long* q = (const unsigned long long*)p;
  union { unsigned long long u[2]; half8 h; } cv;
  cv.u[0] = __hip_atomic_load(q,     __ATOMIC_RELAXED, __HIP_MEMORY_SCOPE_AGENT);
  cv.u[1] = __hip_atomic_load(q + 1, __ATOMIC_RELAXED, __HIP_MEMORY_SCOPE_AGENT);
  return cv.h;
}
__device__ __forceinline__ void agstore_h4(void* p, half4v h) {
  union { half4v h; unsigned long long u; } cv; cv.h = h;
  agstore_u64(p, cv.u);
}
__device__ __forceinline__ void agstore_h2(void* p, _Float16 h0, _Float16 h1) {
  union { _Float16 h[2]; unsigned u; } cv; cv.h[0] = h0; cv.h[1] = h1;
  agstore_u32(p, cv.u);
}

template <int M, int N>
__device__ __forceinline__ void zero_acc(float4v (&a)[M][N]) {
  #pragma unroll
  for (int m = 0; m < M; ++m) {
    #pragma unroll
    for (int n = 0; n < N; ++n) {
      #pragma unroll
      for (int r = 0; r < 4; ++r) a[m][n][r] = 0.f;
    }
  }
}

// convert 8 consecutive f32 -> f16 MFMA fragment
__device__ __forceinline__ half8 ld_w8_f16(const float* p) {
  float4 f0 = *(const float4*)(p);
  float4 f1 = *(const float4*)(p + 4);
  half8 h;
  h[0] = (_Float16)f0.x; h[1] = (_Float16)f0.y; h[2] = (_Float16)f0.z; h[3] = (_Float16)f0.w;
  h[4] = (_Float16)f1.x; h[5] = (_Float16)f1.y; h[6] = (_Float16)f1.z; h[7] = (_Float16)f1.w;
  return h;
}

// Load Whh-style [3072][1024] weight slice for (hidden-slice s, K-eighth w) into
// register-resident B-fragments (layout: lane holds B[k][ncol], ncol=lane&15, k=(lane>>4)*8+j).
// 8 waves: wave w covers K columns [w*128, (w+1)*128): 4 ks-subtiles of 32.
__device__ __forceinline__ void load_W_frags(const float* __restrict__ W, int s, int w,
                                             int lane, half8 BW[6][4]) {
  const int l15 = lane & 15, lq = lane >> 4;
  #pragma unroll
  for (int n = 0; n < 6; ++n) {
    const int row = (n >> 1) * 1024 + s * 32 + (n & 1) * 16 + l15;
    const float* rp = W + (size_t)row * HH + (w << 7) + (lq << 3);
    #pragma unroll
    for (int ks = 0; ks < 4; ++ks) BW[n][ks] = ld_w8_f16(rp + ks * 32);
  }
}

// ---- all-to-all epoch-flag group barrier (no RMW contention) ----
// arrive: after syncthreads (all waves' agent stores drained to coherence point),
// block stores its own epoch flag — one store, private 64B line.
__device__ __forceinline__ void bar_arrive(unsigned* ef, int lb, unsigned ep1) {
  __syncthreads();
  if (threadIdx.x == 0) agstore_u32(&ef[lb * 16], ep1);
}
// full-group wait (used once at the end): lanes 0..31 of wave 0 poll all 32 flags.
__device__ __forceinline__ void bar_wait(unsigned* ef, unsigned ep) {
  if (threadIdx.x < 32) {
    while (agload_u32(&ef[threadIdx.x * 16]) < ep)
      __builtin_amdgcn_s_sleep(1);
  }
  __syncthreads();
}

// per-wave producer wait: wave w consumes K-columns produced by blocks
// s' = w*4 .. w*4+3 only. Lanes 0..3 gather those 4 epoch flags; ballot; spin.
// No __syncthreads — waves decouple; LDS hazards covered by per-step barriers.
// Safety: 8 waves × 4 producers = all 32 group blocks confirmed before a block's
// epilogue (which is behind __syncthreads of all 8 waves) overwrites h(t-1).
__device__ __forceinline__ void wait_my4(unsigned* ef, int s0, unsigned ep, int lane) {
  for (;;) {
    unsigned f = 0xFFFFFFFFu;
    if (lane < 4) f = agload_u32(&ef[(s0 + lane) * 16]);
    unsigned long long m = __ballot(f >= ep);
    if (m == ~0ull) break;
    __builtin_amdgcn_s_sleep(1);
  }
}

// Init-free grid barrier: overwrites poison, needs no pre-zeroed memory.
__device__ __forceinline__ void flag_barrier(unsigned* flags, int blk, int tid, unsigned val) {
  __syncthreads();
  if (tid == 0) agstore_u32(&flags[blk], val);
  if (tid < 256) {
    while (agload_u32(&flags[tid]) != val)
      __builtin_amdgcn_s_sleep(2);
  }
  __syncthreads();
}

// 8-partial sum from LDS
__device__ __forceinline__ float ps8(const float* P, int rw, int cl) {
  float s = 0.f;
  #pragma unroll
  for (int u = 0; u < 8; ++u) s += P[u * 3104 + rw * 97 + cl];
  return s;
}

__global__ __launch_bounds__(512, 2) void ts_fused(
    const float* __restrict__ x,
    const float* __restrict__ eWih, const float* __restrict__ eWhh,
    const float* __restrict__ ebih, const float* __restrict__ ebhh,
    const float* __restrict__ dWih, const float* __restrict__ dWhh,
    const float* __restrict__ dbih, const float* __restrict__ dbhh,
    const float* __restrict__ fciW, const float* __restrict__ fcib,
    const float* __restrict__ fcW,  const float* __restrict__ fcb,
    float* __restrict__ out, char* __restrict__ ws) {
  __shared__ float P[8 * 32 * 97];  // per-wave K-partial sums (99,328 B)
  __shared__ float Q[2 * 32 * 97];  // enc: inn partials (waves 0,1); dec: Q[0] = gi_dec

  _Float16* x2     = (_Float16*)(ws + OFF_X2);
  _Float16* hbuf   = (_Float16*)(ws + OFF_HBUF);
  float* outp      = (float*)(ws + OFF_OUTP);
  unsigned* bar    = (unsigned*)(ws + OFF_BAR);
  unsigned* eflags = (unsigned*)(ws + OFF_EFLAG);
  float* st11      = (float*)(ws + OFF_ST11);
  float* st12      = (float*)(ws + OFF_ST12);
  unsigned* flags  = (unsigned*)(ws + OFF_FLAG);

  const int tid  = threadIdx.x;
  const int blk  = blockIdx.x;
  const int lane = tid & 63;
  const int w    = tid >> 6;   // wave = K-eighth (0..7)
  const int w4   = w << 2;     // first producer block of this wave's K-slice
  const int l15  = lane & 15;
  const int lq   = lane >> 4;
  const int g    = blk & 7;    // batch group: rows g*32..g*32+31
  const int s    = blk >> 3;   // hidden slice: cols s*32..s*32+31 (local-block id in group)
  const int eb   = tid >> 4;   // epilogue: local batch row 0..31
  const int jq   = tid & 15;   // epilogue: j-pair, j = jq*2+e (e<2)
  const int colb = s * 32 + jq * 2;

  // ---------------- phase 0: smoothing (64 blk × 64 thr × 4 chains) + zero-init ----------------
  if (blk < 64) {
    if (tid < 64) {
      const int idx = blk * 64 + tid;   // 4096 threads: (b, d-quad)
      const int b = idx >> 4, dq = idx & 15, d = dq * 4;
      const float* xp = x + (size_t)b * LL * DD + d;
      _Float16* x2p = x2 + (size_t)b * LL * DD + d;
      float v1[4] = {0.f, 0.f, 0.f, 0.f}, v2[4] = {0.f, 0.f, 0.f, 0.f};
      #pragma unroll 1
      for (int t0 = 0; t0 < LL; t0 += 8) {
        float4 xb[8];
        #pragma unroll
        for (int u = 0; u < 8; ++u)
          xb[u] = *(const float4*)(xp + (size_t)(t0 + u) * DD);
        #pragma unroll
        for (int u = 0; u < 8; ++u) {
          const int t = t0 + u;
          const float xe[4] = {xb[u].x, xb[u].y, xb[u].z, xb[u].w};
          half4v hv;
          #pragma unroll
          for (int e = 0; e < 4; ++e) {
            v1[e] = (t == 0) ? xe[e] : 0.7f * xe[e] + 0.3f * v1[e];  // alpha=0.3 pass
            v2[e] = (t == 0) ? v1[e] : 0.5f * v1[e] + 0.5f * v2[e];  // beta=0.5 pass
            hv[e] = (_Float16)v2[e];
          }
          agstore_h4(x2p + (size_t)t * DD, hv);  // write-through (cross-XCD read later)
        }
      }
      if (dq == 0) {  // COLS = {1,2}
        union { float f[2]; unsigned long long u; } c1, c2;
        c1.f[0] = v1[1]; c1.f[1] = v1[2];
        c2.f[0] = v2[1]; c2.f[1] = v2[2];
        agstore_u64(&st11[b * 2], c1.u);
        agstore_u64(&st12[b * 2], c2.u);
      }
    }
  } else {
    // zero hbuf (h0=0), outp, bar, eflags — contiguous region, write-through
    unsigned long long* zr = (unsigned long long*)(ws + OFF_HBUF);
    const int NZ = (int)((SZ_HBUF + SZ_OUTP + SZ_BAR + SZ_EFLAG) / 8);
    for (int i = (blk - 64) * 512 + tid; i < NZ; i += 192 * 512) agstore_u64(&zr[i], 0ull);
  }

  // grid barrier #1 — init-free
  flag_barrier(flags, blk, tid, 1u);

  unsigned* ef      = eflags + g * 32 * 16;  // this group's 32 epoch flags
  unsigned* gridbar = bar;

  // ---------------- encoder ----------------
  half8 BW[6][4];                       // Whh slice, register-stationary (96 VGPRs)
  load_W_frags(eWhh, s, w, lane, BW);
  half8 BWi[6];                         // Wih slice (one K=32 subtile), waves 0,1 only
  if (w < 2) {
    #pragma unroll
    for (int n = 0; n < 6; ++n) {
      const int row = (n >> 1) * 1024 + s * 32 + (n & 1) * 16 + l15;
      BWi[n] = ld_w8_f16(eWih + (size_t)row * DD + (w << 5) + (lq << 3));
    }
  }
  float ebr[2], ebz[2], ebin[2], ebhn[2];
  #pragma unroll
  for (int e = 0; e < 2; ++e) {
    const int c = colb + e;
    ebr[e]  = ebih[c] + ebhh[c];                 // r: biases merge
    ebz[e]  = ebih[1024 + c] + ebhh[1024 + c];   // z: biases merge
    ebin[e] = ebih[2048 + c];                    // n: stays separate (r * (hn + bhh_n))
    ebhn[e] = ebhh[2048 + c];
  }
  float hold[2] = {0.f, 0.f};  // fp32 master h for owned (b,j) elements

  #pragma unroll 1
  for (int t = 0; t < LL; ++t) {
    const _Float16* hc = hbuf + (size_t)(t & 1) * BB * HH;
    _Float16* hnx = hbuf + (size_t)((t + 1) & 1) * BB * HH;

    float4v acc[2][6], accI[2][2];
    zero_acc(acc);
    zero_acc(accI);

    if (w < 2) {  // gi partial = x2_t[, K=32 slice w] @ Wih^T : r,z seed acc; inn -> accI
      const _Float16* ap = x2 + (size_t)(g * 32 + l15) * (LL * DD) + (size_t)t * DD + (w << 5) + (lq << 3);
      half8 a0 = *(const half8*)ap;                        // write-once data: plain load safe
      half8 a1 = *(const half8*)(ap + (size_t)16 * LL * DD);
      #pragma unroll
      for (int n = 0; n < 6; ++n) {
        if (n < 4) {
          acc[0][n] = MFMA16(a0, BWi[n], acc[0][n]);
          acc[1][n] = MFMA16(a1, BWi[n], acc[1][n]);
        } else {
          accI[0][n - 4] = MFMA16(a0, BWi[n], accI[0][n - 4]);
          accI[1][n - 4] = MFMA16(a1, BWi[n], accI[1][n - 4]);
        }
      }
    }
    // wait only for THIS wave's 4 producers; t=0: h0 ready via grid barrier #1
    if (t > 0) wait_my4(ef, w4, (unsigned)t, lane);
    // issue ALL h loads first (8 × 16B in flight — one L3 round trip), then MFMA
    half8 a0[4], a1[4];
    #pragma unroll
    for (int ks = 0; ks < 4; ++ks) {
      const _Float16* ap = hc + (size_t)(g * 32 + l15) * HH + (w << 7) + ks * 32 + (lq << 3);
      a0[ks] = agload_h8(ap);
      a1[ks] = agload_h8(ap + 16 * HH);
    }
    #pragma unroll
    for (int ks = 0; ks < 4; ++ks) {
      #pragma unroll
      for (int n = 0; n < 6; ++n) {
        acc[0][n] = MFMA16(a0[ks], BW[n][ks], acc[0][n]);
        acc[1][n] = MFMA16(a1[ks], BW[n][ks], acc[1][n]);
      }
    }
    {  // partials -> LDS  (C-layout: row = m*16+lq*4+r, col = gate*32+(n&1)*16+l15)
      float* Pw = P + w * 3104;
      #pragma unroll
      for (int m = 0; m < 2; ++m) {
        const int row0 = m * 16 + lq * 4;
        #pragma unroll
        for (int n = 0; n < 6; ++n) {
          const int col = (n >> 1) * 32 + (n & 1) * 16 + l15;
          #pragma unroll
          for (int r = 0; r < 4; ++r) Pw[(row0 + r) * 97 + col] = acc[m][n][r];
        }
      }
      if (w < 2) {
        float* Qw = Q + w * 3104;
        #pragma unroll
        for (int m = 0; m < 2; ++m) {
          const int row0 = m * 16 + lq * 4;
          #pragma unroll
          for (int n2 = 0; n2 < 2; ++n2) {
            const int col = n2 * 16 + l15;
            #pragma unroll
            for (int r = 0; r < 4; ++r) Qw[(row0 + r) * 97 + col] = accI[m][n2][r];
          }
        }
      }
    }
    __syncthreads();
    {  // GRU epilogue, fp32 (each thread owns 2 h elements)
      _Float16 hh[2];
      #pragma unroll
      for (int e = 0; e < 2; ++e) {
        const int j = jq * 2 + e;
        const float Sr = ps8(P, eb, j);        // ir+hr
        const float Sz = ps8(P, eb, 32 + j);   // iz+hz
        const float Hn = ps8(P, eb, 64 + j);   // hn only
        const float rr = 1.f / (1.f + __expf(-(Sr + ebr[e])));
        const float zz = 1.f / (1.f + __expf(-(Sz + ebz[e])));
        const float gin = Q[eb * 97 + j] + Q[3104 + eb * 97 + j];
        const float aN = (gin + ebin[e]) + rr * (Hn + ebhn[e]);
        const float nn = 1.f - 2.f / (1.f + __expf(2.f * aN));
        const float hv = (1.f - zz) * nn + zz * hold[e];
        hold[e] = hv;
        hh[e] = (_Float16)hv;
      }
      agstore_h2(hnx + (size_t)(g * 32 + eb) * HH + s * 32 + jq * 2, hh[0], hh[1]);
    }
    bar_arrive(ef, s, (unsigned)(t + 1));
  }

  // ---------------- D0: gi_dec = hT@dWih^T + dbih (-> Q[0]), h0d = hT@fciW^T + fcib ----------------
  {
    wait_my4(ef, w4, (unsigned)LL, lane);  // hT ready (this wave's K-slice)
    const _Float16* hT = hbuf;   // parity: after 512 steps hT lives in buf0
    float4v acc[2][6];
    zero_acc(acc);
    #pragma unroll 1
    for (int ks = 0; ks < 4; ++ks) {
      const _Float16* ap = hT + (size_t)(g * 32 + l15) * HH + (w << 7) + ks * 32 + (lq << 3);
      half8 a0 = agload_h8(ap);
      half8 a1 = agload_h8(ap + 16 * HH);
      #pragma unroll
      for (int n = 0; n < 6; ++n) {
        const int row = (n >> 1) * 1024 + s * 32 + (n & 1) * 16 + l15;
        half8 bf = ld_w8_f16(dWih + (size_t)row * HH + (w << 7) + ks * 32 + (lq << 3));
        acc[0][n] = MFMA16(a0, bf, acc[0][n]);
        acc[1][n] = MFMA16(a1, bf, acc[1][n]);
      }
    }
    {
      float* Pw = P + w * 3104;
      #pragma unroll
      for (int m = 0; m < 2; ++m) {
        const int row0 = m * 16 + lq * 4;
        #pragma unroll
        for (int n = 0; n < 6; ++n) {
          const int col = (n >> 1) * 32 + (n & 1) * 16 + l15;
          #pragma unroll
          for (int r = 0; r < 4; ++r) Pw[(row0 + r) * 97 + col] = acc[m][n][r];
        }
      }
    }
    __syncthreads();
    #pragma unroll
    for (int e = 0; e < 2; ++e) {   // Q[0] <- gi_dec (+ dbih), constant for all 24 steps
      const int j = jq * 2 + e;
      #pragma unroll
      for (int gate = 0; gate < 3; ++gate) {
        const int col = gate * 32 + j;
        Q[eb * 97 + col] = ps8(P, eb, col) + dbih[gate * 1024 + s * 32 + j];
      }
    }
    __syncthreads();
    // h0d = hT @ fciW^T + fcib  (same K-slice producers already confirmed >= LL)
    float4v acc2[2][2];
    zero_acc(acc2);
    #pragma unroll 1
    for (int ks = 0; ks < 4; ++ks) {
      const _Float16* ap = hT + (size_t)(g * 32 + l15) * HH + (w << 7) + ks * 32 + (lq << 3);
      half8 a0 = agload_h8(ap);
      half8 a1 = agload_h8(ap + 16 * HH);
      #pragma unroll
      for (int n2 = 0; n2 < 2; ++n2) {
        const int row = s * 32 + n2 * 16 + l15;
        half8 bf = ld_w8_f16(fciW + (size_t)row * HH + (w << 7) + ks * 32 + (lq << 3));
        acc2[0][n2] = MFMA16(a0, bf, acc2[0][n2]);
        acc2[1][n2] = MFMA16(a1, bf, acc2[1][n2]);
      }
    }
    {
      float* Pw = P + w * 3104;
      #pragma unroll
      for (int m = 0; m < 2; ++m) {
        const int row0 = m * 16 + lq * 4;
        #pragma unroll
        for (int n2 = 0; n2 < 2; ++n2) {
          const int col = n2 * 16 + l15;
          #pragma unroll
          for (int r = 0; r < 4; ++r) Pw[(row0 + r) * 97 + col] = acc2[m][n2][r];
        }
      }
    }
    __syncthreads();
    {
      _Float16 hh[2];
      #pragma unroll
      for (int e = 0; e < 2; ++e) {
        const int j = jq * 2 + e;
        const float v = ps8(P, eb, j) + fcib[s * 32 + j];
        hold[e] = v;
        hh[e] = (_Float16)v;
      }
      // write h0d to buf1 (buf0 = hT still being read by group peers until their waits pass)
      agstore_h2(hbuf + (size_t)BB * HH + (size_t)(g * 32 + eb) * HH + s * 32 + jq * 2, hh[0], hh[1]);
    }
    bar_arrive(ef, s, (unsigned)(LL + 1));
  }

  // ---------------- decoder ----------------
  load_W_frags(dWhh, s, w, lane, BW);  // reuse register file
  float dbr_[2], dbz_[2], dbn_[2], fw0[2], fw1[2];
  #pragma unroll
  for (int e = 0; e < 2; ++e) {
    const int c = colb + e;
    dbr_[e] = dbhh[c];
    dbz_[e] = dbhh[1024 + c];
    dbn_[e] = dbhh[2048 + c];
    fw0[e] = fcW[c];           // fc_W [2][1024]
    fw1[e] = fcW[1024 + c];
  }
  #pragma unroll 1
  for (int t = 0; t < SS; ++t) {
    wait_my4(ef, w4, (unsigned)(LL + 1 + t), lane);
    const _Float16* hc = hbuf + (size_t)((t + 1) & 1) * BB * HH;  // t=0 reads buf1 (h0d)
    _Float16* hnx = hbuf + (size_t)(t & 1) * BB * HH;
    float4v acc[2][6];
    zero_acc(acc);
    half8 a0[4], a1[4];
    #pragma unroll
    for (int ks = 0; ks < 4; ++ks) {
      const _Float16* ap = hc + (size_t)(g * 32 + l15) * HH + (w << 7) + ks * 32 + (lq << 3);
      a0[ks] = agload_h8(ap);
      a1[ks] = agload_h8(ap + 16 * HH);
    }
    #pragma unroll
    for (int ks = 0; ks < 4; ++ks) {
      #pragma unroll
      for (int n = 0; n < 6; ++n) {
        acc[0][n] = MFMA16(a0[ks], BW[n][ks], acc[0][n]);
        acc[1][n] = MFMA16(a1[ks], BW[n][ks], acc[1][n]);
      }
    }
    {
      float* Pw = P + w * 3104;
      #pragma unroll
      for (int m = 0; m < 2; ++m) {
        const int row0 = m * 16 + lq * 4;
        #pragma unroll
        for (int n = 0; n < 6; ++n) {
          const int col = (n >> 1) * 32 + (n & 1) * 16 + l15;
          #pragma unroll
          for (int r = 0; r < 4; ++r) Pw[(row0 + r) * 97 + col] = acc[m][n][r];
        }
      }
    }
    __syncthreads();
    {
      _Float16 hh[2];
      float p0 = 0.f, p1 = 0.f;
      #pragma unroll
      for (int e = 0; e < 2; ++e) {
        const int j = jq * 2 + e;
        const float rr = 1.f / (1.f + __expf(-(ps8(P, eb, j) + Q[eb * 97 + j] + dbr_[e])));
        const float zz = 1.f / (1.f + __expf(-(ps8(P, eb, 32 + j) + Q[eb * 97 + 32 + j] + dbz_[e])));
        const float aN = Q[eb * 97 + 64 + j] + rr * (ps8(P, eb, 64 + j) + dbn_[e]);
        const float nn = 1.f - 2.f / (1.f + __expf(2.f * aN));
        const float hv = (1.f - zz) * nn + zz * hold[e];
        hold[e] = hv;
        hh[e] = (_Float16)hv;
        p0 += hv * fw0[e];
        p1 += hv * fw1[e];
      }
      agstore_h2(hnx + (size_t)(g * 32 + eb) * HH + s * 32 + jq * 2, hh[0], hh[1]);
      // fc fused: reduce over this CU's 32 hidden cols (16 adjacent lanes share a batch row)
      p0 += __shfl_xor(p0, 1); p0 += __shfl_xor(p0, 2); p0 += __shfl_xor(p0, 4); p0 += __shfl_xor(p0, 8);
      p1 += __shfl_xor(p1, 1); p1 += __shfl_xor(p1, 2); p1 += __shfl_xor(p1, 4); p1 += __shfl_xor(p1, 8);
      if (jq == 0) {
        atomicAdd(&outp[((g * 32 + eb) * SS + t) * 2 + 0], p0);
        atomicAdd(&outp[((g * 32 + eb) * SS + t) * 2 + 1], p1);
      }
    }
    bar_arrive(ef, s, (unsigned)(LL + 2 + t));
  }

  // ---------------- grid barrier #2: group flag-barrier, then 8 leader RMWs ----------------
  bar_wait(ef, (unsigned)(LL + 1 + SS));   // group done (outp atomics drained pre-arrive)
  if (s == 0 && tid == 0) atomicAdd(gridbar, 1u);
  if (tid == 0) {
    while (agload_u32(gridbar) < 8u) __builtin_amdgcn_s_sleep(1);
  }
  __syncthreads();

  // ---------------- final: fc bias + two shifted de-smoothing passes ----------------
  if (blk < 2 && tid < 256) {
    const int t5 = blk * 256 + tid;   // 512 threads: (b, c)
    const int b = t5 >> 1, c = t5 & 1;
    const float s2v = st12[b * 2 + c];
    const float s1v = st11[b * 2 + c];
    const float bias = fcb[c];
    float o0p = 0.f, o1p = 0.f;
    #pragma unroll 1
    for (int t = 0; t < SS; ++t) {
      const float o0 = outp[(b * SS + t) * 2 + c] + bias;
      const float o1 = 2.f * o0 - ((t == 0) ? s2v : o0p);              // (o0-0.5*st2)/0.5
      const float o2 = (o1 - 0.3f * ((t == 0) ? s1v : o1p)) * (1.f / 0.7f);
      o0p = o0; o1p = o1;
      out[b * 48 + t * 2 + c] = o2;
    }
  }

  // replay-safety: leave flags at 0 for the next launch (all blocks have passed
  // flag-barrier #1 before any block reaches here — guaranteed by grid barrier #2)
  if (tid == 0) agstore_u32(&flags[blk], 0u);
}

extern "C" void kernel_launch(void* const* d_in, const int* in_sizes, int n_in,
                              void* d_out, int out_size, void* d_ws, size_t ws_size,
                              hipStream_t stream) {
  (void)in_sizes; (void)n_in; (void)out_size; (void)ws_size;
  const float* x    = (const float*)d_in[0];
  const float* eWih = (const float*)d_in[1];
  const float* eWhh = (const float*)d_in[2];
  const float* ebih = (const float*)d_in[3];
  const float* ebhh = (const float*)d_in[4];
  const float* dWih = (const float*)d_in[5];
  const float* dWhh = (const float*)d_in[6];
  const float* dbih = (const float*)d_in[7];
  const float* dbhh = (const float*)d_in[8];
  const float* fciW = (const float*)d_in[9];
  const float* fcib = (const float*)d_in[10];
  const float* fcW  = (const float*)d_in[11];
  const float* fcb  = (const float*)d_in[12];
  float* out = (float*)d_out;
  char* ws = (char*)d_ws;

  ts_fused<<<dim3(256), dim3(512), 0, stream>>>(
      x, eWih, eWhh, ebih, ebhh, dWih, dWhh, dbih, dbhh,
      fciW, fcib, fcW, fcb, out, ws);
}

// Round 6
// 3048.333 us; speedup vs baseline: 1.2286x; 1.0095x over previous
//
#include <hip/hip_runtime.h>

typedef _Float16 half8  __attribute__((ext_vector_type(8)));
typedef _Float16 half4v __attribute__((ext_vector_type(4)));
typedef float    float4v __attribute__((ext_vector_type(4)));

#define MFMA16(a, b, c) __builtin_amdgcn_mfma_f32_16x16x32_f16((a), (b), (c), 0, 0, 0)

constexpr int BB = 256;   // batch
constexpr int LL = 512;   // encoder seq len
constexpr int DD = 64;    // input dim
constexpr int HH = 1024;  // hidden (enc == dec)
constexpr int SS = 24;    // decoder steps

// LDS partial-sum pitch (even -> float2-aligned epilogue reads)
constexpr int PP   = 98;        // row pitch (floats)
constexpr int WSTR = 32 * PP;   // per-wave tile stride (floats)

// workspace layout (~17.8 MB total) — identical to the r2 passing kernel
constexpr size_t OFF_X2    = 0;                          // [B][L][D] f16 (smoothed input)
constexpr size_t SZ_X2     = (size_t)BB * LL * DD * 2;
constexpr size_t OFF_HBUF  = OFF_X2 + SZ_X2;             // [2][B][H] f16 h double-buffer
constexpr size_t SZ_HBUF   = (size_t)2 * BB * HH * 2;
constexpr size_t OFF_OUTP  = OFF_HBUF + SZ_HBUF;         // [B][S][2] f32 pre-desmooth out
constexpr size_t SZ_OUTP   = (size_t)BB * SS * 2 * 4;
constexpr size_t OFF_BAR   = OFF_OUTP + SZ_OUTP;         // grid leader counter
constexpr size_t SZ_BAR    = 32 * 4;
constexpr size_t OFF_EFLAG = OFF_BAR + SZ_BAR;           // 8 groups × 32 epoch flags, 64B stride
constexpr size_t SZ_EFLAG  = (size_t)8 * 32 * 16 * 4;
constexpr size_t OFF_ST11  = OFF_EFLAG + SZ_EFLAG;       // [B][2] f32
constexpr size_t OFF_ST12  = OFF_ST11 + 2048;            // [B][2] f32
constexpr size_t OFF_FLAG  = OFF_ST12 + 2048;            // [256] u32 init-free flag barrier

// ---- agent-scope (cross-XCD coherent, cache-bypassing) accessors ----
__device__ __forceinline__ void agstore_u64(void* p, unsigned long long v) {
  __hip_atomic_store((unsigned long long*)p, v, __ATOMIC_RELAXED, __HIP_MEMORY_SCOPE_AGENT);
}
__device__ __forceinline__ void agstore_u32(void* p, unsigned v) {
  __hip_atomic_store((unsigned*)p, v, __ATOMIC_RELAXED, __HIP_MEMORY_SCOPE_AGENT);
}
__device__ __forceinline__ unsigned agload_u32(const unsigned* p) {
  return __hip_atomic_load(p, __ATOMIC_RELAXED, __HIP_MEMORY_SCOPE_AGENT);
}
__device__ __forceinline__ half8 agload_h8(const _Float16* p) {
  const unsigned long long* q = (const unsigned long long*)p;
  union { unsigned long long u[2]; half8 h; } cv;
  cv.u[0] = __hip_atomic_load(q,     __ATOMIC_RELAXED, __HIP_MEMORY_SCOPE_AGENT);
  cv.u[1] = __hip_atomic_load(q + 1, __ATOMIC_RELAXED, __HIP_MEMORY_SCOPE_AGENT);
  return cv.h;
}
__device__ __forceinline__ void agstore_h4(void* p, half4v h) {
  union { half4v h; unsigned long long u; } cv; cv.h = h;
  agstore_u64(p, cv.u);
}
__device__ __forceinline__ void agstore_h2(void* p, _Float16 h0, _Float16 h1) {
  union { _Float16 h[2]; unsigned u; } cv; cv.h[0] = h0; cv.h[1] = h1;
  agstore_u32(p, cv.u);
}

template <int M, int N>
__device__ __forceinline__ void zero_acc(float4v (&a)[M][N]) {
  #pragma unroll
  for (int m = 0; m < M; ++m) {
    #pragma unroll
    for (int n = 0; n < N; ++n) {
      #pragma unroll
      for (int r = 0; r < 4; ++r) a[m][n][r] = 0.f;
    }
  }
}

// convert 8 consecutive f32 -> f16 MFMA fragment
__device__ __forceinline__ half8 ld_w8_f16(const float* p) {
  float4 f0 = *(const float4*)(p);
  float4 f1 = *(const float4*)(p + 4);
  half8 h;
  h[0] = (_Float16)f0.x; h[1] = (_Float16)f0.y; h[2] = (_Float16)f0.z; h[3] = (_Float16)f0.w;
  h[4] = (_Float16)f1.x; h[5] = (_Float16)f1.y; h[6] = (_Float16)f1.z; h[7] = (_Float16)f1.w;
  return h;
}

// Load Whh-style [3072][1024] weight slice for (hidden-slice s, K-eighth w) into
// register-resident B-fragments (layout: lane holds B[k][ncol], ncol=lane&15, k=(lane>>4)*8+j).
// 8 waves: wave w covers K columns [w*128, (w+1)*128): 4 ks-subtiles of 32.
__device__ __forceinline__ void load_W_frags(const float* __restrict__ W, int s, int w,
                                             int lane, half8 BW[6][4]) {
  const int l15 = lane & 15, lq = lane >> 4;
  #pragma unroll
  for (int n = 0; n < 6; ++n) {
    const int row = (n >> 1) * 1024 + s * 32 + (n & 1) * 16 + l15;
    const float* rp = W + (size_t)row * HH + (w << 7) + (lq << 3);
    #pragma unroll
    for (int ks = 0; ks < 4; ++ks) BW[n][ks] = ld_w8_f16(rp + ks * 32);
  }
}

// ---- all-to-all epoch-flag group barrier (no RMW contention) ----
// arrive: after syncthreads (all waves' agent stores drained to coherence point),
// block stores its own epoch flag — one store, private 64B line.
__device__ __forceinline__ void bar_arrive(unsigned* ef, int lb, unsigned ep1) {
  __syncthreads();
  if (threadIdx.x == 0) agstore_u32(&ef[lb * 16], ep1);
}
// full-group wait (used once at the end): lanes 0..31 of wave 0 poll all 32 flags.
__device__ __forceinline__ void bar_wait(unsigned* ef, unsigned ep) {
  if (threadIdx.x < 32) {
    while (agload_u32(&ef[threadIdx.x * 16]) < ep)
      __builtin_amdgcn_s_sleep(1);
  }
  __syncthreads();
}

// per-wave producer wait: wave w consumes K-columns produced by blocks s' = w*4..w*4+3.
// Lanes 0..3 gather those 4 epoch flags; ballot; spin. No __syncthreads — waves decouple;
// LDS hazards covered by per-step barriers. Safety: 8 waves × 4 producers = all 32 group
// blocks confirmed before a block's epilogue (behind __syncthreads) overwrites h(t-1).
__device__ __forceinline__ void wait_my4(unsigned* ef, int s0, unsigned ep, int lane) {
  for (;;) {
    unsigned f = 0xFFFFFFFFu;
    if (lane < 4) f = agload_u32(&ef[(s0 + lane) * 16]);
    unsigned long long m = __ballot(f >= ep);
    if (m == ~0ull) break;
    __builtin_amdgcn_s_sleep(1);
  }
}

// Init-free grid barrier: overwrites poison, needs no pre-zeroed memory.
__device__ __forceinline__ void flag_barrier(unsigned* flags, int blk, int tid, unsigned val) {
  __syncthreads();
  if (tid == 0) agstore_u32(&flags[blk], val);
  if (tid < 256) {
    while (agload_u32(&flags[tid]) != val)
      __builtin_amdgcn_s_sleep(2);
  }
  __syncthreads();
}

// 8-partial float2 sum from LDS (even col -> 8B aligned ds_read_b64)
__device__ __forceinline__ float2 ps8v(const float* P, int rw, int cl) {
  float2 s = {0.f, 0.f};
  #pragma unroll
  for (int u = 0; u < 8; ++u) {
    const float2 v = *(const float2*)&P[u * WSTR + rw * PP + cl];
    s.x += v.x; s.y += v.y;
  }
  return s;
}

__global__ __launch_bounds__(512, 2) void ts_fused(
    const float* __restrict__ x,
    const float* __restrict__ eWih, const float* __restrict__ eWhh,
    const float* __restrict__ ebih, const float* __restrict__ ebhh,
    const float* __restrict__ dWih, const float* __restrict__ dWhh,
    const float* __restrict__ dbih, const float* __restrict__ dbhh,
    const float* __restrict__ fciW, const float* __restrict__ fcib,
    const float* __restrict__ fcW,  const float* __restrict__ fcb,
    float* __restrict__ out, char* __restrict__ ws) {
  __shared__ float P[8 * WSTR];  // per-wave K-partial sums (100,352 B)
  __shared__ float Q[2 * WSTR];  // enc: inn partials (waves 0,1); dec: Q[0] = gi_dec

  _Float16* x2     = (_Float16*)(ws + OFF_X2);
  _Float16* hbuf   = (_Float16*)(ws + OFF_HBUF);
  float* outp      = (float*)(ws + OFF_OUTP);
  unsigned* bar    = (unsigned*)(ws + OFF_BAR);
  unsigned* eflags = (unsigned*)(ws + OFF_EFLAG);
  float* st11      = (float*)(ws + OFF_ST11);
  float* st12      = (float*)(ws + OFF_ST12);
  unsigned* flags  = (unsigned*)(ws + OFF_FLAG);

  const int tid  = threadIdx.x;
  const int blk  = blockIdx.x;
  const int lane = tid & 63;
  const int w    = tid >> 6;   // wave = K-eighth (0..7)
  const int w4   = w << 2;     // first producer block of this wave's K-slice
  const int l15  = lane & 15;
  const int lq   = lane >> 4;
  const int g    = blk & 7;    // batch group: rows g*32..g*32+31
  const int s    = blk >> 3;   // hidden slice: cols s*32..s*32+31 (local-block id in group)
  const int eb   = tid >> 4;   // epilogue: local batch row 0..31
  const int jq   = tid & 15;   // epilogue: j-pair, j = jq*2+e (e<2)
  const int colb = s * 32 + jq * 2;

  // ---------------- phase 0: smoothing (64 blk × 64 thr × 4 chains) + zero-init ----------------
  if (blk < 64) {
    if (tid < 64) {
      const int idx = blk * 64 + tid;   // 4096 threads: (b, d-quad)
      const int b = idx >> 4, dq = idx & 15, d = dq * 4;
      const float* xp = x + (size_t)b * LL * DD + d;
      _Float16* x2p = x2 + (size_t)b * LL * DD + d;
      float v1[4] = {0.f, 0.f, 0.f, 0.f}, v2[4] = {0.f, 0.f, 0.f, 0.f};
      #pragma unroll 1
      for (int t0 = 0; t0 < LL; t0 += 8) {
        float4 xb[8];
        #pragma unroll
        for (int u = 0; u < 8; ++u)
          xb[u] = *(const float4*)(xp + (size_t)(t0 + u) * DD);
        #pragma unroll
        for (int u = 0; u < 8; ++u) {
          const int t = t0 + u;
          const float xe[4] = {xb[u].x, xb[u].y, xb[u].z, xb[u].w};
          half4v hv;
          #pragma unroll
          for (int e = 0; e < 4; ++e) {
            v1[e] = (t == 0) ? xe[e] : 0.7f * xe[e] + 0.3f * v1[e];  // alpha=0.3 pass
            v2[e] = (t == 0) ? v1[e] : 0.5f * v1[e] + 0.5f * v2[e];  // beta=0.5 pass
            hv[e] = (_Float16)v2[e];
          }
          agstore_h4(x2p + (size_t)t * DD, hv);  // write-through (cross-XCD read later)
        }
      }
      if (dq == 0) {  // COLS = {1,2}
        union { float f[2]; unsigned long long u; } c1, c2;
        c1.f[0] = v1[1]; c1.f[1] = v1[2];
        c2.f[0] = v2[1]; c2.f[1] = v2[2];
        agstore_u64(&st11[b * 2], c1.u);
        agstore_u64(&st12[b * 2], c2.u);
      }
    }
  } else {
    // zero hbuf (h0=0), outp, bar, eflags — contiguous region, write-through
    unsigned long long* zr = (unsigned long long*)(ws + OFF_HBUF);
    const int NZ = (int)((SZ_HBUF + SZ_OUTP + SZ_BAR + SZ_EFLAG) / 8);
    for (int i = (blk - 64) * 512 + tid; i < NZ; i += 192 * 512) agstore_u64(&zr[i], 0ull);
  }

  // grid barrier #1 — init-free
  flag_barrier(flags, blk, tid, 1u);

  unsigned* ef      = eflags + g * 32 * 16;  // this group's 32 epoch flags
  unsigned* gridbar = bar;

  // ---------------- encoder ----------------
  half8 BW[6][4];                       // Whh slice, register-stationary (96 VGPRs)
  load_W_frags(eWhh, s, w, lane, BW);
  half8 BWi[6];                         // Wih slice (one K=32 subtile), waves 0,1 only
  if (w < 2) {
    #pragma unroll
    for (int n = 0; n < 6; ++n) {
      const int row = (n >> 1) * 1024 + s * 32 + (n & 1) * 16 + l15;
      BWi[n] = ld_w8_f16(eWih + (size_t)row * DD + (w << 5) + (lq << 3));
    }
  }
  float ebr[2], ebz[2], ebin[2], ebhn[2];
  #pragma unroll
  for (int e = 0; e < 2; ++e) {
    const int c = colb + e;
    ebr[e]  = ebih[c] + ebhh[c];                 // r: biases merge
    ebz[e]  = ebih[1024 + c] + ebhh[1024 + c];   // z: biases merge
    ebin[e] = ebih[2048 + c];                    // n: stays separate (r * (hn + bhh_n))
    ebhn[e] = ebhh[2048 + c];
  }
  float hold[2] = {0.f, 0.f};  // fp32 master h for owned (b,j) elements

  #pragma unroll 1
  for (int t = 0; t < LL; ++t) {
    const _Float16* hc = hbuf + (size_t)(t & 1) * BB * HH;
    _Float16* hnx = hbuf + (size_t)((t + 1) & 1) * BB * HH;

    float4v acc[2][6], accI[2][2];
    zero_acc(acc);
    zero_acc(accI);

    if (w < 2) {  // gi partial = x2_t[, K=32 slice w] @ Wih^T : r,z seed acc; inn -> accI
      const _Float16* ap = x2 + (size_t)(g * 32 + l15) * (LL * DD) + (size_t)t * DD + (w << 5) + (lq << 3);
      half8 a0 = *(const half8*)ap;                        // write-once data: plain load safe
      half8 a1 = *(const half8*)(ap + (size_t)16 * LL * DD);
      #pragma unroll
      for (int n = 0; n < 6; ++n) {
        if (n < 4) {
          acc[0][n] = MFMA16(a0, BWi[n], acc[0][n]);
          acc[1][n] = MFMA16(a1, BWi[n], acc[1][n]);
        } else {
          accI[0][n - 4] = MFMA16(a0, BWi[n], accI[0][n - 4]);
          accI[1][n - 4] = MFMA16(a1, BWi[n], accI[1][n - 4]);
        }
      }
    }
    // wait only for THIS wave's 4 producers; t=0: h0 ready via grid barrier #1
    if (t > 0) wait_my4(ef, w4, (unsigned)t, lane);
    // issue ALL h loads first (8 × 16B in flight — one L3 round trip), then MFMA
    half8 a0[4], a1[4];
    #pragma unroll
    for (int ks = 0; ks < 4; ++ks) {
      const _Float16* ap = hc + (size_t)(g * 32 + l15) * HH + (w << 7) + ks * 32 + (lq << 3);
      a0[ks] = agload_h8(ap);
      a1[ks] = agload_h8(ap + 16 * HH);
    }
    #pragma unroll
    for (int ks = 0; ks < 4; ++ks) {
      #pragma unroll
      for (int n = 0; n < 6; ++n) {
        acc[0][n] = MFMA16(a0[ks], BW[n][ks], acc[0][n]);
        acc[1][n] = MFMA16(a1[ks], BW[n][ks], acc[1][n]);
      }
    }
    {  // partials -> LDS  (C-layout: row = m*16+lq*4+r, col = gate*32+(n&1)*16+l15)
      float* Pw = P + w * WSTR;
      #pragma unroll
      for (int m = 0; m < 2; ++m) {
        const int row0 = m * 16 + lq * 4;
        #pragma unroll
        for (int n = 0; n < 6; ++n) {
          const int col = (n >> 1) * 32 + (n & 1) * 16 + l15;
          #pragma unroll
          for (int r = 0; r < 4; ++r) Pw[(row0 + r) * PP + col] = acc[m][n][r];
        }
      }
      if (w < 2) {
        float* Qw = Q + w * WSTR;
        #pragma unroll
        for (int m = 0; m < 2; ++m) {
          const int row0 = m * 16 + lq * 4;
          #pragma unroll
          for (int n2 = 0; n2 < 2; ++n2) {
            const int col = n2 * 16 + l15;
            #pragma unroll
            for (int r = 0; r < 4; ++r) Qw[(row0 + r) * PP + col] = accI[m][n2][r];
          }
        }
      }
    }
    __syncthreads();
    {  // GRU epilogue, fp32 (each thread owns 2 h elements; float2 LDS reads)
      const int j0 = jq * 2;
      const float2 Sr2 = ps8v(P, eb, j0);
      const float2 Sz2 = ps8v(P, eb, 32 + j0);
      const float2 Hn2 = ps8v(P, eb, 64 + j0);
      const float2 Gi0 = *(const float2*)&Q[eb * PP + j0];
      const float2 Gi1 = *(const float2*)&Q[WSTR + eb * PP + j0];
      const float Sr[2] = {Sr2.x, Sr2.y};
      const float Sz[2] = {Sz2.x, Sz2.y};
      const float Hn[2] = {Hn2.x, Hn2.y};
      const float Gi[2] = {Gi0.x + Gi1.x, Gi0.y + Gi1.y};
      _Float16 hh[2];
      #pragma unroll
      for (int e = 0; e < 2; ++e) {
        const float rr = 1.f / (1.f + __expf(-(Sr[e] + ebr[e])));
        const float zz = 1.f / (1.f + __expf(-(Sz[e] + ebz[e])));
        const float aN = (Gi[e] + ebin[e]) + rr * (Hn[e] + ebhn[e]);
        const float nn = 1.f - 2.f / (1.f + __expf(2.f * aN));
        const float hv = (1.f - zz) * nn + zz * hold[e];
        hold[e] = hv;
        hh[e] = (_Float16)hv;
      }
      agstore_h2(hnx + (size_t)(g * 32 + eb) * HH + s * 32 + j0, hh[0], hh[1]);
    }
    bar_arrive(ef, s, (unsigned)(t + 1));
  }

  // ---------------- D0: gi_dec = hT@dWih^T + dbih (-> Q[0]), h0d = hT@fciW^T + fcib ----------------
  {
    wait_my4(ef, w4, (unsigned)LL, lane);  // hT ready (this wave's K-slice)
    const _Float16* hT = hbuf;   // parity: after 512 steps hT lives in buf0
    float4v acc[2][6];
    zero_acc(acc);
    #pragma unroll 1
    for (int ks = 0; ks < 4; ++ks) {
      const _Float16* ap = hT + (size_t)(g * 32 + l15) * HH + (w << 7) + ks * 32 + (lq << 3);
      half8 a0 = agload_h8(ap);
      half8 a1 = agload_h8(ap + 16 * HH);
      #pragma unroll
      for (int n = 0; n < 6; ++n) {
        const int row = (n >> 1) * 1024 + s * 32 + (n & 1) * 16 + l15;
        half8 bf = ld_w8_f16(dWih + (size_t)row * HH + (w << 7) + ks * 32 + (lq << 3));
        acc[0][n] = MFMA16(a0, bf, acc[0][n]);
        acc[1][n] = MFMA16(a1, bf, acc[1][n]);
      }
    }
    {
      float* Pw = P + w * WSTR;
      #pragma unroll
      for (int m = 0; m < 2; ++m) {
        const int row0 = m * 16 + lq * 4;
        #pragma unroll
        for (int n = 0; n < 6; ++n) {
          const int col = (n >> 1) * 32 + (n & 1) * 16 + l15;
          #pragma unroll
          for (int r = 0; r < 4; ++r) Pw[(row0 + r) * PP + col] = acc[m][n][r];
        }
      }
    }
    __syncthreads();
    {
      const int j0 = jq * 2;
      #pragma unroll
      for (int gate = 0; gate < 3; ++gate) {   // Q[0] <- gi_dec (+ dbih), constant for 24 steps
        const int col = gate * 32 + j0;
        float2 v = ps8v(P, eb, col);
        v.x += dbih[gate * 1024 + s * 32 + j0];
        v.y += dbih[gate * 1024 + s * 32 + j0 + 1];
        *(float2*)&Q[eb * PP + col] = v;
      }
    }
    __syncthreads();
    // h0d = hT @ fciW^T + fcib  (same K-slice producers already confirmed >= LL)
    float4v acc2[2][2];
    zero_acc(acc2);
    #pragma unroll 1
    for (int ks = 0; ks < 4; ++ks) {
      const _Float16* ap = hT + (size_t)(g * 32 + l15) * HH + (w << 7) + ks * 32 + (lq << 3);
      half8 a0 = agload_h8(ap);
      half8 a1 = agload_h8(ap + 16 * HH);
      #pragma unroll
      for (int n2 = 0; n2 < 2; ++n2) {
        const int row = s * 32 + n2 * 16 + l15;
        half8 bf = ld_w8_f16(fciW + (size_t)row * HH + (w << 7) + ks * 32 + (lq << 3));
        acc2[0][n2] = MFMA16(a0, bf, acc2[0][n2]);
        acc2[1][n2] = MFMA16(a1, bf, acc2[1][n2]);
      }
    }
    {
      float* Pw = P + w * WSTR;
      #pragma unroll
      for (int m = 0; m < 2; ++m) {
        const int row0 = m * 16 + lq * 4;
        #pragma unroll
        for (int n2 = 0; n2 < 2; ++n2) {
          const int col = n2 * 16 + l15;
          #pragma unroll
          for (int r = 0; r < 4; ++r) Pw[(row0 + r) * PP + col] = acc2[m][n2][r];
        }
      }
    }
    __syncthreads();
    {
      const int j0 = jq * 2;
      float2 v = ps8v(P, eb, j0);
      v.x += fcib[s * 32 + j0];
      v.y += fcib[s * 32 + j0 + 1];
      hold[0] = v.x; hold[1] = v.y;
      // write h0d to buf1 (buf0 = hT still being read by group peers until their waits pass)
      agstore_h2(hbuf + (size_t)BB * HH + (size_t)(g * 32 + eb) * HH + s * 32 + j0,
                 (_Float16)v.x, (_Float16)v.y);
    }
    bar_arrive(ef, s, (unsigned)(LL + 1));
  }

  // ---------------- decoder ----------------
  load_W_frags(dWhh, s, w, lane, BW);  // reuse register file
  float dbr_[2], dbz_[2], dbn_[2], fw0[2], fw1[2];
  #pragma unroll
  for (int e = 0; e < 2; ++e) {
    const int c = colb + e;
    dbr_[e] = dbhh[c];
    dbz_[e] = dbhh[1024 + c];
    dbn_[e] = dbhh[2048 + c];
    fw0[e] = fcW[c];           // fc_W [2][1024]
    fw1[e] = fcW[1024 + c];
  }
  #pragma unroll 1
  for (int t = 0; t < SS; ++t) {
    wait_my4(ef, w4, (unsigned)(LL + 1 + t), lane);
    const _Float16* hc = hbuf + (size_t)((t + 1) & 1) * BB * HH;  // t=0 reads buf1 (h0d)
    _Float16* hnx = hbuf + (size_t)(t & 1) * BB * HH;
    float4v acc[2][6];
    zero_acc(acc);
    half8 a0[4], a1[4];
    #pragma unroll
    for (int ks = 0; ks < 4; ++ks) {
      const _Float16* ap = hc + (size_t)(g * 32 + l15) * HH + (w << 7) + ks * 32 + (lq << 3);
      a0[ks] = agload_h8(ap);
      a1[ks] = agload_h8(ap + 16 * HH);
    }
    #pragma unroll
    for (int ks = 0; ks < 4; ++ks) {
      #pragma unroll
      for (int n = 0; n < 6; ++n) {
        acc[0][n] = MFMA16(a0[ks], BW[n][ks], acc[0][n]);
        acc[1][n] = MFMA16(a1[ks], BW[n][ks], acc[1][n]);
      }
    }
    {
      float* Pw = P + w * WSTR;
      #pragma unroll
      for (int m = 0; m < 2; ++m) {
        const int row0 = m * 16 + lq * 4;
        #pragma unroll
        for (int n = 0; n < 6; ++n) {
          const int col = (n >> 1) * 32 + (n & 1) * 16 + l15;
          #pragma unroll
          for (int r = 0; r < 4; ++r) Pw[(row0 + r) * PP + col] = acc[m][n][r];
        }
      }
    }
    __syncthreads();
    {
      const int j0 = jq * 2;
      const float2 Pr2 = ps8v(P, eb, j0);
      const float2 Pz2 = ps8v(P, eb, 32 + j0);
      const float2 Pn2 = ps8v(P, eb, 64 + j0);
      const float2 Qr2 = *(const float2*)&Q[eb * PP + j0];
      const float2 Qz2 = *(const float2*)&Q[eb * PP + 32 + j0];
      const float2 Qn2 = *(const float2*)&Q[eb * PP + 64 + j0];
      const float Pr[2] = {Pr2.x, Pr2.y}, Pz[2] = {Pz2.x, Pz2.y}, Pn[2] = {Pn2.x, Pn2.y};
      const float Qr[2] = {Qr2.x, Qr2.y}, Qz[2] = {Qz2.x, Qz2.y}, Qn[2] = {Qn2.x, Qn2.y};
      _Float16 hh[2];
      float p0 = 0.f, p1 = 0.f;
      #pragma unroll
      for (int e = 0; e < 2; ++e) {
        const float rr = 1.f / (1.f + __expf(-(Pr[e] + Qr[e] + dbr_[e])));
        const float zz = 1.f / (1.f + __expf(-(Pz[e] + Qz[e] + dbz_[e])));
        const float aN = Qn[e] + rr * (Pn[e] + dbn_[e]);
        const float nn = 1.f - 2.f / (1.f + __expf(2.f * aN));
        const float hv = (1.f - zz) * nn + zz * hold[e];
        hold[e] = hv;
        hh[e] = (_Float16)hv;
        p0 += hv * fw0[e];
        p1 += hv * fw1[e];
      }
      agstore_h2(hnx + (size_t)(g * 32 + eb) * HH + s * 32 + j0, hh[0], hh[1]);
      // fc fused: reduce over this CU's 32 hidden cols (16 adjacent lanes share a batch row)
      p0 += __shfl_xor(p0, 1); p0 += __shfl_xor(p0, 2); p0 += __shfl_xor(p0, 4); p0 += __shfl_xor(p0, 8);
      p1 += __shfl_xor(p1, 1); p1 += __shfl_xor(p1, 2); p1 += __shfl_xor(p1, 4); p1 += __shfl_xor(p1, 8);
      if (jq == 0) {
        atomicAdd(&outp[((g * 32 + eb) * SS + t) * 2 + 0], p0);
        atomicAdd(&outp[((g * 32 + eb) * SS + t) * 2 + 1], p1);
      }
    }
    bar_arrive(ef, s, (unsigned)(LL + 2 + t));
  }

  // ---------------- grid barrier #2: group flag-barrier, then 8 leader RMWs ----------------
  bar_wait(ef, (unsigned)(LL + 1 + SS));   // group done (outp atomics drained pre-arrive)
  if (s == 0 && tid == 0) atomicAdd(gridbar, 1u);
  if (tid == 0) {
    while (agload_u32(gridbar) < 8u) __builtin_amdgcn_s_sleep(1);
  }
  __syncthreads();

  // ---------------- final: fc bias + two shifted de-smoothing passes ----------------
  if (blk < 2 && tid < 256) {
    const int t5 = blk * 256 + tid;   // 512 threads: (b, c)
    const int b = t5 >> 1, c = t5 & 1;
    const float s2v = st12[b * 2 + c];
    const float s1v = st11[b * 2 + c];
    const float bias = fcb[c];
    float o0p = 0.f, o1p = 0.f;
    #pragma unroll 1
    for (int t = 0; t < SS; ++t) {
      const float o0 = outp[(b * SS + t) * 2 + c] + bias;
      const float o1 = 2.f * o0 - ((t == 0) ? s2v : o0p);              // (o0-0.5*st2)/0.5
      const float o2 = (o1 - 0.3f * ((t == 0) ? s1v : o1p)) * (1.f / 0.7f);
      o0p = o0; o1p = o1;
      out[b * 48 + t * 2 + c] = o2;
    }
  }

  // replay-safety: leave flags at 0 for the next launch (all blocks have passed
  // flag-barrier #1 before any block reaches here — guaranteed by grid barrier #2)
  if (tid == 0) agstore_u32(&flags[blk], 0u);
}

extern "C" void kernel_launch(void* const* d_in, const int* in_sizes, int n_in,
                              void* d_out, int out_size, void* d_ws, size_t ws_size,
                              hipStream_t stream) {
  (void)in_sizes; (void)n_in; (void)out_size; (void)ws_size;
  const float* x    = (const float*)d_in[0];
  const float* eWih = (const float*)d_in[1];
  const float* eWhh = (const float*)d_in[2];
  const float* ebih = (const float*)d_in[3];
  const float* ebhh = (const float*)d_in[4];
  const float* dWih = (const float*)d_in[5];
  const float* dWhh = (const float*)d_in[6];
  const float* dbih = (const float*)d_in[7];
  const float* dbhh = (const float*)d_in[8];
  const float* fciW = (const float*)d_in[9];
  const float* fcib = (const float*)d_in[10];
  const float* fcW  = (const float*)d_in[11];
  const float* fcb  = (const float*)d_in[12];
  float* out = (float*)d_out;
  char* ws = (char*)d_ws;

  ts_fused<<<dim3(256), dim3(512), 0, stream>>>(
      x, eWih, eWhh, ebih, ebhh, dWih, dWhh, dbih, dbhh,
      fciW, fcib, fcW, fcb, out, ws);
}